// Round 7
// baseline (280.796 us; speedup 1.0000x reference)
//
#include <hip/hip_runtime.h>

#define NH 4
#define ND 16
#define HD 64
#define IN_DIM 128
#define NEG_SLOPE 0.2f
#define NR 8          // dst ranges (one per XCD)

typedef short bf8 __attribute__((ext_vector_type(8)));   // 8 bf16 in 4 VGPRs
typedef float f4  __attribute__((ext_vector_type(4)));

__device__ inline unsigned short f2bf(float f) {   // RNE fp32 -> bf16
  unsigned u = __float_as_uint(f);
  u += 0x7FFFu + ((u >> 16) & 1u);
  return (unsigned short)(u >> 16);
}

// ---- K1: feat(bf16) = x @ fc_W via MFMA, + el/er per node ----
__global__ __launch_bounds__(256) void k1_mfma(
    const float* __restrict__ x, const float* __restrict__ fcW,
    const float* __restrict__ attn_l, const float* __restrict__ attn_r,
    unsigned short* __restrict__ featb, float4* __restrict__ el4, float4* __restrict__ er4,
    int n)
{
  __shared__ unsigned short wt[HD][IN_DIM + 8];   // W^T bf16, padded
  for (int idx = threadIdx.x; idx < IN_DIM * HD; idx += 256) {
    int k = idx >> 6, j = idx & 63;
    wt[j][k] = f2bf(fcW[idx]);
  }
  __syncthreads();

  const int w  = threadIdx.x >> 6;    // wave 0..3
  const int l  = threadIdx.x & 63;
  const int lr = l & 15;
  const int lg = l >> 4;
  const int rowbase = blockIdx.x * 64 + w * 16;

  int arow = rowbase + lr;
  if (arow >= n) arow = n - 1;                     // clamp; stores predicated
  const float* xp = x + (size_t)arow * IN_DIM + lg * 8;

  f4 acc[4] = {};                                  // one per n-tile (= head)
#pragma unroll
  for (int kc = 0; kc < 4; ++kc) {
    float4 a0 = *(const float4*)(xp + kc * 32);
    float4 a1 = *(const float4*)(xp + kc * 32 + 4);
    bf8 af;
    af[0] = (short)f2bf(a0.x); af[1] = (short)f2bf(a0.y);
    af[2] = (short)f2bf(a0.z); af[3] = (short)f2bf(a0.w);
    af[4] = (short)f2bf(a1.x); af[5] = (short)f2bf(a1.y);
    af[6] = (short)f2bf(a1.z); af[7] = (short)f2bf(a1.w);
#pragma unroll
    for (int nt = 0; nt < 4; ++nt) {
      bf8 bfr = *(const bf8*)&wt[nt * 16 + lr][kc * 32 + lg * 8];
      acc[nt] = __builtin_amdgcn_mfma_f32_16x16x32_bf16(af, bfr, acc[nt], 0, 0, 0);
    }
  }

  float al[NH], ar[NH];
#pragma unroll
  for (int h = 0; h < NH; ++h) { al[h] = attn_l[h * 16 + lr]; ar[h] = attn_r[h * 16 + lr]; }

#pragma unroll
  for (int r = 0; r < 4; ++r) {
    int grow = rowbase + lg * 4 + r;
    bool ok = grow < n;
    if (ok) {
#pragma unroll
      for (int nt = 0; nt < 4; ++nt)
        featb[(size_t)grow * HD + nt * 16 + lr] = f2bf(acc[nt][r]);
    }
    float pl[NH], pr[NH];
#pragma unroll
    for (int h = 0; h < NH; ++h) { pl[h] = acc[h][r] * al[h]; pr[h] = acc[h][r] * ar[h]; }
#pragma unroll
    for (int off = 1; off < 16; off <<= 1) {
#pragma unroll
      for (int h = 0; h < NH; ++h) {
        pl[h] += __shfl_xor(pl[h], off);
        pr[h] += __shfl_xor(pr[h], off);
      }
    }
    if (ok && lr == 0) {
      el4[grow] = make_float4(pl[0], pl[1], pl[2], pl[3]);
      er4[grow] = make_float4(pr[0], pr[1], pr[2], pr[3]);
    }
  }
}

// ---- P0: per-range edge counts (8 bins, LDS) ----
__global__ __launch_bounds__(256) void k_rangecnt(
    const int* __restrict__ dst, int* __restrict__ rangecnt, int ne, int chunk)
{
  __shared__ int lc[NR];
  if (threadIdx.x < NR) lc[threadIdx.x] = 0;
  __syncthreads();
  for (int e = blockIdx.x * 256 + threadIdx.x; e < ne; e += gridDim.x * 256)
    atomicAdd(&lc[dst[e] / chunk], 1);
  __syncthreads();
  if (threadIdx.x < NR) atomicAdd(&rangecnt[threadIdx.x], lc[threadIdx.x]);
}

// ---- P1: bucket bases = exclusive prefix of rangecnt ----
__global__ void k_binit(const int* __restrict__ rangecnt, int* __restrict__ bnext)
{
  if (threadIdx.x == 0) {
    int r = 0;
    for (int b = 0; b < NR; ++b) { bnext[b] = r; r += rangecnt[b]; }
  }
}

// ---- P2: multisplit edges into 8 contiguous dst-range buckets (coalesced) ----
#define BKV 4
__global__ __launch_bounds__(256) void k_bucket(
    const int* __restrict__ src, const int* __restrict__ dst, const int* __restrict__ et,
    int* __restrict__ bnext, uint2* __restrict__ ebuf, int ne, int chunk)
{
  __shared__ int scnt[NR], sbase[NR], gbase[NR];
  __shared__ uint2 sbuf[256 * BKV];      // 8 KB
  for (int base = blockIdx.x * (256 * BKV); base < ne; base += gridDim.x * (256 * BKV)) {
    if (threadIdx.x < NR) scnt[threadIdx.x] = 0;
    __syncthreads();
    int rr0 = 0, rr1 = 0, rr2 = 0, rr3 = 0;
    int sl0 = 0, sl1 = 0, sl2 = 0, sl3 = 0;
    uint2 rc0, rc1, rc2, rc3;
    bool hv0, hv1, hv2, hv3;
    {
      int e;
      e = base + 0 * 256 + threadIdx.x; hv0 = e < ne;
      if (hv0) { int d = dst[e]; rr0 = d / chunk;
        rc0.x = (unsigned)src[e] | ((unsigned)et[e] << 17); rc0.y = (unsigned)d;
        sl0 = atomicAdd(&scnt[rr0], 1); }
      e = base + 1 * 256 + threadIdx.x; hv1 = e < ne;
      if (hv1) { int d = dst[e]; rr1 = d / chunk;
        rc1.x = (unsigned)src[e] | ((unsigned)et[e] << 17); rc1.y = (unsigned)d;
        sl1 = atomicAdd(&scnt[rr1], 1); }
      e = base + 2 * 256 + threadIdx.x; hv2 = e < ne;
      if (hv2) { int d = dst[e]; rr2 = d / chunk;
        rc2.x = (unsigned)src[e] | ((unsigned)et[e] << 17); rc2.y = (unsigned)d;
        sl2 = atomicAdd(&scnt[rr2], 1); }
      e = base + 3 * 256 + threadIdx.x; hv3 = e < ne;
      if (hv3) { int d = dst[e]; rr3 = d / chunk;
        rc3.x = (unsigned)src[e] | ((unsigned)et[e] << 17); rc3.y = (unsigned)d;
        sl3 = atomicAdd(&scnt[rr3], 1); }
    }
    __syncthreads();
    if (threadIdx.x == 0) {
      int r = 0;
#pragma unroll
      for (int b = 0; b < NR; ++b) { sbase[b] = r; r += scnt[b]; }
    }
    __syncthreads();
    if (threadIdx.x < NR) gbase[threadIdx.x] = atomicAdd(&bnext[threadIdx.x], scnt[threadIdx.x]);
    if (hv0) sbuf[sbase[rr0] + sl0] = rc0;
    if (hv1) sbuf[sbase[rr1] + sl1] = rc1;
    if (hv2) sbuf[sbase[rr2] + sl2] = rc2;
    if (hv3) sbuf[sbase[rr3] + sl3] = rc3;
    __syncthreads();
    for (int b = 0; b < NR; ++b) {
      int c = scnt[b], gb = gbase[b], sb = sbase[b];
      for (int i = threadIdx.x; i < c; i += 256)
        ebuf[gb + i] = sbuf[sb + i];
    }
    __syncthreads();
  }
}

__device__ inline void seg_of(const int* __restrict__ rangecnt, int rr, int& lo, int& hi)
{
  int r = 0, lo_ = 0;
#pragma unroll
  for (int b = 0; b < NR; ++b) { if (b == rr) lo_ = r; r += rangecnt[b]; }
  lo = lo_; hi = lo_ + rangecnt[rr];
}

// ---- P3: per-range histogram from bucket (XCD-local atomics) ----
__global__ __launch_bounds__(256) void k_hist_b(
    const uint2* __restrict__ ebuf, const int* __restrict__ rangecnt,
    int* __restrict__ cnt)
{
  const int rr = blockIdx.x & 7, g = blockIdx.x >> 3, G = gridDim.x >> 3;
  int lo, hi; seg_of(rangecnt, rr, lo, hi);
  for (int i = lo + g * 256 + threadIdx.x; i < hi; i += G * 256)
    atomicAdd(&cnt[ebuf[i].y], 1);
}

// ---- K2a: per-block partial sums of counts ----
__global__ __launch_bounds__(512) void k_psum(
    const int* __restrict__ cnt, int* __restrict__ blocksum, int n)
{
  __shared__ int ws[8];
  int i = blockIdx.x * 512 + threadIdx.x;
  int c = (i < n) ? cnt[i] : 0;
#pragma unroll
  for (int off = 32; off >= 1; off >>= 1) c += __shfl_xor(c, off);
  int lane = threadIdx.x & 63, w = threadIdx.x >> 6;
  if (lane == 0) ws[w] = c;
  __syncthreads();
  if (threadIdx.x == 0) {
    int r = 0;
#pragma unroll
    for (int k = 0; k < 8; ++k) r += ws[k];
    blocksum[blockIdx.x] = r;
  }
}

// ---- K2b: scan block sums (nb <= 256) + tiny ee[t][h] fused ----
__global__ __launch_bounds__(256) void k_scan_blk(
    const int* __restrict__ blocksum, int* __restrict__ blockbase,
    int nb, int* __restrict__ rowptr, int n, int ne,
    const float* __restrict__ edge_emb, const float* __restrict__ fc_e_W,
    const float* __restrict__ attn_e, float* __restrict__ ee)
{
  __shared__ int ws[4], wb[4];
  __shared__ float sef[8][128];
  int t = threadIdx.x;
  int c = (t < nb) ? blocksum[t] : 0;
  int lane = t & 63, w = t >> 6;
  int inc = c;
#pragma unroll
  for (int off = 1; off < 64; off <<= 1) {
    int v = __shfl_up(inc, off);
    if (lane >= off) inc += v;
  }
  if (lane == 63) ws[w] = inc;
  if (t < 128) {
    for (int r = 0; r < 8; ++r) {
      float acc = 0.f;
#pragma unroll
      for (int k = 0; k < 32; ++k) acc = fmaf(edge_emb[r * 32 + k], fc_e_W[k * 128 + t], acc);
      sef[r][t] = acc;
    }
  }
  __syncthreads();
  if (t == 0) { int r = 0; for (int k = 0; k < 4; ++k) { wb[k] = r; r += ws[k]; } }
  if (t < 32) {
    int r = t >> 2, h = t & 3;
    float acc = 0.f;
#pragma unroll
    for (int e2 = 0; e2 < 32; ++e2) acc += sef[r][h * 32 + e2] * attn_e[h * 32 + e2];
    ee[r * NH + h] = acc;
  }
  __syncthreads();
  if (t < nb) blockbase[t] = wb[w] + inc - c;
  if (t == 0) rowptr[n] = ne;
}

// ---- K2c: block-local scan + base ----
__global__ __launch_bounds__(512) void k_scan_apply(
    int* __restrict__ rowptr, const int* __restrict__ blockbase,
    int* __restrict__ next, int n)
{
  __shared__ int ws[8], wb[8];
  int i = blockIdx.x * 512 + threadIdx.x;
  int c = (i < n) ? rowptr[i] : 0;
  int lane = threadIdx.x & 63, w = threadIdx.x >> 6;
  int inc = c;
#pragma unroll
  for (int off = 1; off < 64; off <<= 1) {
    int v = __shfl_up(inc, off);
    if (lane >= off) inc += v;
  }
  if (lane == 63) ws[w] = inc;
  __syncthreads();
  if (threadIdx.x == 0) { int r = 0; for (int k = 0; k < 8; ++k) { wb[k] = r; r += ws[k]; } }
  __syncthreads();
  int ex = blockbase[blockIdx.x] + wb[w] + inc - c;
  if (i < n) { rowptr[i] = ex; next[i] = ex; }
}

// ---- P4: per-range scatter from bucket (recs region stays in one L2) ----
__global__ __launch_bounds__(256) void k_scatter_b(
    const uint2* __restrict__ ebuf, const int* __restrict__ rangecnt,
    int* __restrict__ next, unsigned* __restrict__ recs)
{
  const int rr = blockIdx.x & 7, g = blockIdx.x >> 3, G = gridDim.x >> 3;
  int lo, hi; seg_of(rangecnt, rr, lo, hi);
  for (int i = lo + g * 256 + threadIdx.x; i < hi; i += G * 256) {
    uint2 r = ebuf[i];
    int pos = atomicAdd(&next[r.y], 1);
    recs[pos] = r.x;
  }
}

// ---- K4: wave per dst, 8 edges in flight (8-lane groups), bf16 feat gather ----
__global__ __launch_bounds__(256) void k_agg(
    const int* __restrict__ rowptr, const unsigned* __restrict__ recs,
    const float* __restrict__ el, const float* __restrict__ er, const float* __restrict__ eeg,
    const uint4* __restrict__ featq, float* __restrict__ out, int n)
{
  __shared__ float s_ee[32];
  if (threadIdx.x < 32) s_ee[threadIdx.x] = eeg[threadIdx.x];
  __syncthreads();
  int d = (blockIdx.x * 256 + threadIdx.x) >> 6;
  if (d >= n) return;
  int lane = threadIdx.x & 63;
  int q = lane >> 3;          // edge slot 0..7
  int l = lane & 7;           // dim octet: dims 8l..8l+7
  int h = l >> 1;             // head
  int beg = rowptr[d], end = rowptr[d + 1];
  float erd = er[d * NH + h];
  float a0 = 0.f, a1 = 0.f, a2 = 0.f, a3 = 0.f;
  float a4 = 0.f, a5 = 0.f, a6 = 0.f, a7 = 0.f, den = 0.f;
  for (int i = beg + q; i < end; i += 8) {
    unsigned rr = recs[i];
    int s = rr & 0x1FFFF;
    int t = rr >> 17;
    float sv = el[s * NH + h] + erd + s_ee[t * NH + h];
    sv = sv > 0.f ? sv : NEG_SLOPE * sv;
    float p = __expf(sv);
    den += p;
    uint4 u = featq[s * 8 + l];               // 8 packed bf16 dims
    a0 = fmaf(p, __uint_as_float(u.x << 16), a0);
    a1 = fmaf(p, __uint_as_float(u.x & 0xFFFF0000u), a1);
    a2 = fmaf(p, __uint_as_float(u.y << 16), a2);
    a3 = fmaf(p, __uint_as_float(u.y & 0xFFFF0000u), a3);
    a4 = fmaf(p, __uint_as_float(u.z << 16), a4);
    a5 = fmaf(p, __uint_as_float(u.z & 0xFFFF0000u), a5);
    a6 = fmaf(p, __uint_as_float(u.w << 16), a6);
    a7 = fmaf(p, __uint_as_float(u.w & 0xFFFF0000u), a7);
  }
#pragma unroll
  for (int off = 8; off <= 32; off <<= 1) {
    den += __shfl_xor(den, off);
    a0 += __shfl_xor(a0, off); a1 += __shfl_xor(a1, off);
    a2 += __shfl_xor(a2, off); a3 += __shfl_xor(a3, off);
    a4 += __shfl_xor(a4, off); a5 += __shfl_xor(a5, off);
    a6 += __shfl_xor(a6, off); a7 += __shfl_xor(a7, off);
  }
  if (q == 0) {
    float inv = den > 0.f ? 1.f / den : 0.f;
    float4* op = (float4*)out + (size_t)d * 16 + l * 2;
    op[0] = make_float4(a0 * inv, a1 * inv, a2 * inv, a3 * inv);
    op[1] = make_float4(a4 * inv, a5 * inv, a6 * inv, a7 * inv);
  }
}

extern "C" void kernel_launch(void* const* d_in, const int* in_sizes, int n_in,
                              void* d_out, int out_size, void* d_ws, size_t ws_size,
                              hipStream_t stream)
{
  const float* x        = (const float*)d_in[0];
  const int*   src      = (const int*)d_in[1];
  const int*   dst      = (const int*)d_in[2];
  const int*   etype    = (const int*)d_in[3];
  const float* fcW      = (const float*)d_in[4];
  const float* fceW     = (const float*)d_in[5];
  const float* edge_emb = (const float*)d_in[6];
  const float* attn_l   = (const float*)d_in[7];
  const float* attn_r   = (const float*)d_in[8];
  const float* attn_e   = (const float*)d_in[9];
  float* out = (float*)d_out;

  const int n  = in_sizes[0] / IN_DIM;   // 100000
  const int ne = in_sizes[1];            // 1600000
  const int nb = (n + 511) / 512;        // scan blocks (<=256)
  const int chunk = (n + NR - 1) / NR;   // dst-range width

  char* ws = (char*)d_ws;
  size_t off = 0;
  // ebuf (edge buckets) overlays featb: ebuf dead before k1_mfma writes featb
  unsigned short* featb = (unsigned short*)(ws + off);
  uint2* ebuf = (uint2*)(ws + off);
  size_t ovl = (size_t)n * HD * sizeof(unsigned short);        // 12.8 MB
  size_t ovl2 = (size_t)ne * sizeof(uint2);                    // 12.8 MB
  off += (ovl > ovl2 ? ovl : ovl2);
  float* el    = (float*)(ws + off); off += (size_t)n * NH * sizeof(float);
  float* er    = (float*)(ws + off); off += (size_t)n * NH * sizeof(float);
  float* ee    = (float*)(ws + off); off += 256;
  int* rowptr  = (int*)(ws + off);   off += ((size_t)n + 1) * sizeof(int);
  int* rangecnt= (int*)(ws + off);   off += NR * sizeof(int);
  int* bnext   = (int*)(ws + off);   off += NR * sizeof(int);
  int* next    = (int*)(ws + off);   off += (size_t)n * sizeof(int);
  int* blocksum= (int*)(ws + off);   off += (size_t)nb * sizeof(int);
  int* blockbase=(int*)(ws + off);   off += (size_t)nb * sizeof(int);
  unsigned* recs = (unsigned*)(ws + off); off += (size_t)ne * sizeof(unsigned);

  // zero rowptr[0..n] + rangecnt[8] + bnext[8] in one memset
  hipMemsetAsync(rowptr, 0, ((size_t)n + 1 + 2 * NR) * sizeof(int), stream);

  k_rangecnt<<<512, 256, 0, stream>>>(dst, rangecnt, ne, chunk);
  k_binit<<<1, 64, 0, stream>>>(rangecnt, bnext);
  k_bucket<<<512, 256, 0, stream>>>(src, dst, etype, bnext, ebuf, ne, chunk);
  k_hist_b<<<1024, 256, 0, stream>>>(ebuf, rangecnt, rowptr);
  k_psum<<<nb, 512, 0, stream>>>(rowptr, blocksum, n);
  k_scan_blk<<<1, 256, 0, stream>>>(blocksum, blockbase, nb, rowptr, n, ne,
                                    edge_emb, fceW, attn_e, ee);
  k_scan_apply<<<nb, 512, 0, stream>>>(rowptr, blockbase, next, n);
  k_scatter_b<<<1024, 256, 0, stream>>>(ebuf, rangecnt, next, recs);
  k1_mfma<<<(n + 63) / 64, 256, 0, stream>>>(x, fcW, attn_l, attn_r, featb,
                                             (float4*)el, (float4*)er, n);
  k_agg<<<((size_t)n * 64 + 255) / 256, 256, 0, stream>>>(rowptr, recs, el, er, ee,
                                                          (const uint4*)featb, out, n);
}